// Round 9
// baseline (16.398 us; speedup 1.0000x reference)
//
#include <hip/hip_runtime.h>

#define NP 8
#define NB 160
#define NA 32
#define NATYPE 16
#define NPOLY 11
#define MIN_SEP 4
#define DVALID (1 << 16)
#define NWG (NP * NB)        // 1280
#define NSLOT (NB * 8)       // 1280 (b2, acc) slots per b1

// One wg per (pose, b1). No LDS, no barriers: each wave writes its own
// partial (pure write). Thread t owns slots t, t+256, ..., t+1024.
__global__ __launch_bounds__(256) void hbond_main(
    const float* __restrict__ coords,        // (P, N*A, 3)
    const int*   __restrict__ coord_off,     // (P, N)
    const int*   __restrict__ block_type,    // (P, N)
    const int*   __restrict__ min_sep,       // (P, N, N)
    const int*   __restrict__ n_donH,        // (BT,)
    const int*   __restrict__ n_acc,         // (BT,)
    const int*   __restrict__ donH_inds,     // (BT, 4)
    const int*   __restrict__ acc_inds,      // (BT, 8)
    const int*   __restrict__ donor_type,    // (BT, 4)
    const int*   __restrict__ acceptor_type, // (BT, 8)
    const int*   __restrict__ acceptor_hyb,  // (BT, 8)
    const float* __restrict__ pair_params,   // (256, 3)
    const float* __restrict__ pair_poly,     // (256, 11)
    const float* __restrict__ gp,            // (4,)
    float*       __restrict__ partials)      // (NWG*4,) one per wave
{
    const int t  = threadIdx.x;
    const int p  = blockIdx.x / NB;
    const int b1 = blockIdx.x - p * NB;

    // ---- donors for b1 (wave-uniform scalar loads) ----
    const int bt1  = block_type[p * NB + b1];
    const int off1 = coord_off[p * NB + b1];
    const int nd   = n_donH[bt1];
    float4 dv[4];
    #pragma unroll
    for (int dn = 0; dn < 4; ++dn) {
        const int hatom = donH_inds[bt1 * 4 + dn];
        const int dbase = donor_type[bt1 * 4 + dn] * NATYPE;
        const float* Hc = coords + (size_t)(p * (NB * NA) + off1 + hatom) * 3;
        dv[dn] = make_float4(Hc[0], Hc[1], Hc[2],
                             __int_as_float((dbase & 0xff) | ((dn < nd) ? DVALID : 0)));
    }

    const float cut  = gp[0];
    const float emin = gp[1];
    const int   seprow = (p * NB + b1) * NB;

    float energy = 0.0f;

    #pragma unroll
    for (int k = 0; k < NSLOT / 256; ++k) {
        const int i  = k * 256 + t;
        const int b2 = i >> 3;
        const int a  = i & 7;

        // cheap validity (independent loads, pipelined across k)
        const int  sep = min_sep[seprow + b2];
        const int  bt2 = block_type[p * NB + b2];
        const bool ok  = (b2 != b1) && (sep >= MIN_SEP);
        const int  na  = n_acc[bt2];

        float hd0 = 0, hd1 = 0, hd2 = 0, hd3 = 0;
        int   hp0 = 0, hp1 = 0, hp2 = 0, hp3 = 0;
        int   nh = 0, hyb = 0;

        if (ok && a < na) {
            const int ai    = acc_inds[bt2 * 8 + a];
            const int atype = acceptor_type[bt2 * 8 + a];
            hyb             = acceptor_hyb[bt2 * 8 + a];
            const int off2  = coord_off[p * NB + b2];
            const float* Ac = coords + (size_t)(p * (NB * NA) + off2 + ai) * 3;
            const float ax = Ac[0], ay = Ac[1], az = Ac[2];

            #pragma unroll
            for (int dn = 0; dn < 4; ++dn) {
                const int dbits = __float_as_int(dv[dn].w);
                if (!(dbits & DVALID)) continue;   // wave-uniform
                const float dx = dv[dn].x - ax;
                const float dy = dv[dn].y - ay;
                const float dz = dv[dn].z - az;
                const float dd = sqrtf(dx * dx + dy * dy + dz * dz + 1e-12f);
                if (dd < cut) {
                    const int pp = (dbits & 0xff) + atype;
                    hd3 = (nh == 3) ? dd : hd3;  hp3 = (nh == 3) ? pp : hp3;
                    hd2 = (nh == 2) ? dd : hd2;  hp2 = (nh == 2) ? pp : hp2;
                    hd1 = (nh == 1) ? dd : hd1;  hp1 = (nh == 1) ? pp : hp1;
                    hd0 = (nh == 0) ? dd : hd0;  hp0 = (nh == 0) ? pp : hp0;
                    ++nh;
                }
            }
        }

        // rare Horner path (~1% of slots pass the distance filter)
        #pragma unroll
        for (int h = 0; h < 4; ++h) {
            if (!__any(h < nh)) break;
            if (h < nh) {
                const float dd = (h == 0) ? hd0 : (h == 1) ? hd1 : (h == 2) ? hd2 : hd3;
                const int   pp = (h == 0) ? hp0 : (h == 1) ? hp1 : (h == 2) ? hp2 : hp3;
                const float* c = pair_poly + pp * NPOLY;
                float ev = c[0];
                #pragma unroll
                for (int kk = 1; kk < NPOLY; ++kk) ev = ev * dd + c[kk];
                const float w = pair_params[pp * 3 + hyb];
                ev = fmaxf(fminf(ev, 0.0f), emin);
                energy += w * ev;
            }
        }
    }

    // ---- wave-local reduce, one pure write per wave (no barriers) ----
    #pragma unroll
    for (int off = 32; off >= 1; off >>= 1)
        energy += __shfl_down(energy, off, 64);
    const int wv = t >> 6, ln = t & 63;
    if (ln == 0) partials[blockIdx.x * 4 + wv] = energy;
}

// 1 wg: wave wv sums poses 2wv, 2wv+1 (640 partials each, coalesced).
__global__ __launch_bounds__(256) void hbond_reduce(
    const float* __restrict__ partials, float* __restrict__ out)
{
    const int wv = threadIdx.x >> 6, ln = threadIdx.x & 63;
    #pragma unroll
    for (int q = 0; q < 2; ++q) {
        const int pose = wv * 2 + q;
        const float* base = partials + pose * NB * 4;
        float v = 0.0f;
        #pragma unroll
        for (int r = 0; r < 10; ++r) v += base[r * 64 + ln];
        #pragma unroll
        for (int off = 32; off >= 1; off >>= 1)
            v += __shfl_down(v, off, 64);
        if (ln == 0) out[pose] = v;
    }
}

extern "C" void kernel_launch(void* const* d_in, const int* in_sizes, int n_in,
                              void* d_out, int out_size, void* d_ws, size_t ws_size,
                              hipStream_t stream) {
    const float* coords        = (const float*)d_in[0];
    // d_in[1] (dispatch) is the full (p, b1, b2) meshgrid — derived from blockIdx.
    const int*   coord_off     = (const int*)  d_in[2];
    const int*   block_type    = (const int*)  d_in[3];
    const int*   min_sep       = (const int*)  d_in[4];
    const int*   n_donH        = (const int*)  d_in[5];
    const int*   n_acc         = (const int*)  d_in[6];
    const int*   donH_inds     = (const int*)  d_in[7];
    const int*   acc_inds      = (const int*)  d_in[8];
    const int*   donor_type    = (const int*)  d_in[9];
    const int*   acceptor_type = (const int*)  d_in[10];
    const int*   acceptor_hyb  = (const int*)  d_in[11];
    const float* pair_params   = (const float*)d_in[12];
    const float* pair_poly     = (const float*)d_in[13];
    const float* gp            = (const float*)d_in[14];
    float*       partials      = (float*)d_ws;   // NWG*4 floats = 20480 B
    float*       out           = (float*)d_out;

    hbond_main<<<NWG, 256, 0, stream>>>(
        coords, coord_off, block_type, min_sep,
        n_donH, n_acc, donH_inds, acc_inds,
        donor_type, acceptor_type, acceptor_hyb,
        pair_params, pair_poly, gp, partials);

    hbond_reduce<<<1, 256, 0, stream>>>(partials, out);
}

// Round 10
// 14.545 us; speedup vs baseline: 1.1274x; 1.1274x over previous
//
#include <hip/hip_runtime.h>

#define NP 8
#define NB 160
#define NA 32
#define NATYPE 16
#define NPOLY 11
#define MIN_SEP 4
#define DVALID (1 << 16)
#define NBT 2                     // b1 blocks per workgroup
#define NWG_PER_POSE (NB / NBT)   // 80
#define NWG (NP * NWG_PER_POSE)   // 640

// One wg per (pose, 2 x b1). b2info staged once, two ballot-compacted b2
// lists, distance pre-filter, rare Horner. Wave-level partials (no final
// cross-wave reduce/barrier): partials[wg*4 + wave].
__global__ __launch_bounds__(256) void hbond_main(
    const float* __restrict__ coords,        // (P, N*A, 3)
    const int*   __restrict__ coord_off,     // (P, N)
    const int*   __restrict__ block_type,    // (P, N)
    const int*   __restrict__ min_sep,       // (P, N, N)
    const int*   __restrict__ n_donH,        // (BT,)
    const int*   __restrict__ n_acc,         // (BT,)
    const int*   __restrict__ donH_inds,     // (BT, 4)
    const int*   __restrict__ acc_inds,      // (BT, 8)
    const int*   __restrict__ donor_type,    // (BT, 4)
    const int*   __restrict__ acceptor_type, // (BT, 8)
    const int*   __restrict__ acceptor_hyb,  // (BT, 8)
    const float* __restrict__ pair_params,   // (256, 3)
    const float* __restrict__ pair_poly,     // (256, 11)
    const float* __restrict__ gp,            // (4,)
    float*       __restrict__ partials)      // (NWG*4,)
{
    const int t   = threadIdx.x;
    const int p   = blockIdx.x / NWG_PER_POSE;
    const int pr  = blockIdx.x - p * NWG_PER_POSE;
    const int b1a = pr * NBT, b1b = b1a + 1;

    __shared__ int4 b2info[NB];      // (bt2, off2, n_acc, 0)  2560 B
    __shared__ int  b2listA[NB];     //  640 B
    __shared__ int  b2listB[NB];     //  640 B
    __shared__ int  wcA[4], wcB[4];

    const float cut  = gp[0];
    const float emin = gp[1];

    // ---- per-b2 metadata + pair_ok for both b1 (t < 160) ----
    bool okA = false, okB = false;
    if (t < NB) {
        const int bt2  = block_type[p * NB + t];
        const int off2 = coord_off[p * NB + t];
        const int na   = n_acc[bt2];
        okA = (t != b1a) && (min_sep[(p * NB + b1a) * NB + t] >= MIN_SEP);
        okB = (t != b1b) && (min_sep[(p * NB + b1b) * NB + t] >= MIN_SEP);
        b2info[t] = make_int4(bt2, off2, na, 0);
    }

    // ---- donors for both b1 (wave-uniform scalar loads) ----
    float4 dA[4], dB[4];
    {
        const int bt1a = block_type[p * NB + b1a], bt1b = block_type[p * NB + b1b];
        const int off1a = coord_off[p * NB + b1a], off1b = coord_off[p * NB + b1b];
        const int nda = n_donH[bt1a], ndb = n_donH[bt1b];
        #pragma unroll
        for (int dn = 0; dn < 4; ++dn) {
            const float* Ha = coords + (size_t)(p * (NB * NA) + off1a + donH_inds[bt1a * 4 + dn]) * 3;
            const float* Hb = coords + (size_t)(p * (NB * NA) + off1b + donH_inds[bt1b * 4 + dn]) * 3;
            dA[dn] = make_float4(Ha[0], Ha[1], Ha[2],
                __int_as_float(((donor_type[bt1a * 4 + dn] * NATYPE) & 0xff) | ((dn < nda) ? DVALID : 0)));
            dB[dn] = make_float4(Hb[0], Hb[1], Hb[2],
                __int_as_float(((donor_type[bt1b * 4 + dn] * NATYPE) & 0xff) | ((dn < ndb) ? DVALID : 0)));
        }
    }

    // ---- ballot compaction for both lists ----
    const unsigned long long mA = __ballot(okA);
    const unsigned long long mB = __ballot(okB);
    const int wv = t >> 6, ln = t & 63;
    if (ln == 0) { wcA[wv] = __popcll(mA); wcB[wv] = __popcll(mB); }
    __syncthreads();

    int preA = 0, preB = 0, cntA = 0, cntB = 0;
    #pragma unroll
    for (int w = 0; w < 4; ++w) {
        cntA += wcA[w]; cntB += wcB[w];
        if (w < wv) { preA += wcA[w]; preB += wcB[w]; }
    }
    {
        const unsigned long long below = (1ull << ln) - 1ull;
        if (okA) b2listA[preA + __popcll(mA & below)] = t;
        if (okB) b2listB[preB + __popcll(mB & below)] = t;
    }
    __syncthreads();

    // ---- two segment loops ----
    float energy = 0.0f;
    #pragma unroll 1
    for (int seg = 0; seg < 2; ++seg) {
        const int cnt8 = (seg ? cntB : cntA) * 8;
        const int* __restrict__ list = seg ? b2listB : b2listA;
        const float4* dv = seg ? dB : dA;

        for (int i = t; i < cnt8; i += 256) {
            const int b2 = list[i >> 3];
            const int a  = i & 7;
            const int4 info = b2info[b2];

            float hd0 = 0, hd1 = 0, hd2 = 0, hd3 = 0;
            int   hp0 = 0, hp1 = 0, hp2 = 0, hp3 = 0;
            int   nh = 0, hyb = 0;

            if (a < info.z) {
                const int ai    = acc_inds[info.x * 8 + a];
                const int atype = acceptor_type[info.x * 8 + a];
                hyb             = acceptor_hyb[info.x * 8 + a];
                const float* Ac = coords + (size_t)(p * (NB * NA) + info.y + ai) * 3;
                const float ax = Ac[0], ay = Ac[1], az = Ac[2];

                #pragma unroll
                for (int dn = 0; dn < 4; ++dn) {
                    const int dbits = __float_as_int(dv[dn].w);
                    if (!(dbits & DVALID)) continue;   // wave-uniform
                    const float dx = dv[dn].x - ax;
                    const float dy = dv[dn].y - ay;
                    const float dz = dv[dn].z - az;
                    const float dd = sqrtf(dx * dx + dy * dy + dz * dz + 1e-12f);
                    if (dd < cut) {
                        const int pp = (dbits & 0xff) + atype;
                        hd3 = (nh == 3) ? dd : hd3;  hp3 = (nh == 3) ? pp : hp3;
                        hd2 = (nh == 2) ? dd : hd2;  hp2 = (nh == 2) ? pp : hp2;
                        hd1 = (nh == 1) ? dd : hd1;  hp1 = (nh == 1) ? pp : hp1;
                        hd0 = (nh == 0) ? dd : hd0;  hp0 = (nh == 0) ? pp : hp0;
                        ++nh;
                    }
                }
            }

            // rare Horner path (~1% of slots pass the distance filter)
            #pragma unroll
            for (int h = 0; h < 4; ++h) {
                if (!__any(h < nh)) break;
                if (h < nh) {
                    const float dd = (h == 0) ? hd0 : (h == 1) ? hd1 : (h == 2) ? hd2 : hd3;
                    const int   pp = (h == 0) ? hp0 : (h == 1) ? hp1 : (h == 2) ? hp2 : hp3;
                    const float* c = pair_poly + pp * NPOLY;
                    float ev = c[0];
                    #pragma unroll
                    for (int kk = 1; kk < NPOLY; ++kk) ev = ev * dd + c[kk];
                    const float w = pair_params[pp * 3 + hyb];
                    ev = fmaxf(fminf(ev, 0.0f), emin);
                    energy += w * ev;
                }
            }
        }
    }

    // ---- wave-local reduce, one pure write per wave (no extra barrier) ----
    #pragma unroll
    for (int off = 32; off >= 1; off >>= 1)
        energy += __shfl_down(energy, off, 64);
    if (ln == 0) partials[blockIdx.x * 4 + wv] = energy;
}

// 1 wg: wave wv sums poses 2wv, 2wv+1 (320 partials each, coalesced).
__global__ __launch_bounds__(256) void hbond_reduce(
    const float* __restrict__ partials, float* __restrict__ out)
{
    const int wv = threadIdx.x >> 6, ln = threadIdx.x & 63;
    #pragma unroll
    for (int q = 0; q < 2; ++q) {
        const int pose = wv * 2 + q;
        const float* base = partials + pose * NWG_PER_POSE * 4;  // 320 floats
        float v = 0.0f;
        #pragma unroll
        for (int r = 0; r < 5; ++r) v += base[r * 64 + ln];
        #pragma unroll
        for (int off = 32; off >= 1; off >>= 1)
            v += __shfl_down(v, off, 64);
        if (ln == 0) out[pose] = v;
    }
}

extern "C" void kernel_launch(void* const* d_in, const int* in_sizes, int n_in,
                              void* d_out, int out_size, void* d_ws, size_t ws_size,
                              hipStream_t stream) {
    const float* coords        = (const float*)d_in[0];
    // d_in[1] (dispatch) is the full (p, b1, b2) meshgrid — derived from blockIdx.
    const int*   coord_off     = (const int*)  d_in[2];
    const int*   block_type    = (const int*)  d_in[3];
    const int*   min_sep       = (const int*)  d_in[4];
    const int*   n_donH        = (const int*)  d_in[5];
    const int*   n_acc         = (const int*)  d_in[6];
    const int*   donH_inds     = (const int*)  d_in[7];
    const int*   acc_inds      = (const int*)  d_in[8];
    const int*   donor_type    = (const int*)  d_in[9];
    const int*   acceptor_type = (const int*)  d_in[10];
    const int*   acceptor_hyb  = (const int*)  d_in[11];
    const float* pair_params   = (const float*)d_in[12];
    const float* pair_poly     = (const float*)d_in[13];
    const float* gp            = (const float*)d_in[14];
    float*       partials      = (float*)d_ws;   // NWG*4 floats = 10240 B
    float*       out           = (float*)d_out;

    hbond_main<<<NWG, 256, 0, stream>>>(
        coords, coord_off, block_type, min_sep,
        n_donH, n_acc, donH_inds, acc_inds,
        donor_type, acceptor_type, acceptor_hyb,
        pair_params, pair_poly, gp, partials);

    hbond_reduce<<<1, 256, 0, stream>>>(partials, out);
}

// Round 11
// 12.786 us; speedup vs baseline: 1.2825x; 1.1376x over previous
//
#include <hip/hip_runtime.h>

#define NP 8
#define NB 160
#define NA 32
#define NATYPE 16
#define NPOLY 11
#define MIN_SEP 4
#define DVALID (1 << 16)
#define NWG (NP * NB)        // 1280
#define BPW 40               // b2 blocks per wave (160 / 4 waves)

// One wg per (pose, b1); 4 fully independent waves (ZERO barriers).
// Wave wv owns b2 in [wv*40, wv*40+40): stages its own b2info slice,
// ballot-compacts its own sublist (same-wave LDS, no __syncthreads),
// loops over its own slots, writes its own partial.
__global__ __launch_bounds__(256) void hbond_main(
    const float* __restrict__ coords,        // (P, N*A, 3)
    const int*   __restrict__ coord_off,     // (P, N)
    const int*   __restrict__ block_type,    // (P, N)
    const int*   __restrict__ min_sep,       // (P, N, N)
    const int*   __restrict__ n_donH,        // (BT,)
    const int*   __restrict__ n_acc,         // (BT,)
    const int*   __restrict__ donH_inds,     // (BT, 4)
    const int*   __restrict__ acc_inds,      // (BT, 8)
    const int*   __restrict__ donor_type,    // (BT, 4)
    const int*   __restrict__ acceptor_type, // (BT, 8)
    const int*   __restrict__ acceptor_hyb,  // (BT, 8)
    const float* __restrict__ pair_params,   // (256, 3)
    const float* __restrict__ pair_poly,     // (256, 11)
    const float* __restrict__ gp,            // (4,)
    float*       __restrict__ partials)      // (NWG*4,)
{
    const int t  = threadIdx.x;
    const int p  = blockIdx.x / NB;
    const int b1 = blockIdx.x - p * NB;
    const int wv = t >> 6, ln = t & 63;

    __shared__ int2 b2info[NB];    // (bt2 | na<<16, off2)  1280 B
    __shared__ int  b2list[NB];    //  640 B (wave-private 40-slots)

    const float cut  = gp[0];
    const float emin = gp[1];

    // ---- donors for b1 (wave-uniform scalar loads) ----
    const int bt1  = block_type[p * NB + b1];
    const int off1 = coord_off[p * NB + b1];
    const int nd   = n_donH[bt1];
    float4 dv[4];
    #pragma unroll
    for (int dn = 0; dn < 4; ++dn) {
        const int hatom = donH_inds[bt1 * 4 + dn];
        const int dbase = donor_type[bt1 * 4 + dn] * NATYPE;
        const float* Hc = coords + (size_t)(p * (NB * NA) + off1 + hatom) * 3;
        dv[dn] = make_float4(Hc[0], Hc[1], Hc[2],
                             __int_as_float((dbase & 0xff) | ((dn < nd) ? DVALID : 0)));
    }

    // ---- wave-private staging + compaction (no barriers) ----
    bool ok = false;
    if (ln < BPW) {
        const int b2   = wv * BPW + ln;
        const int bt2  = block_type[p * NB + b2];
        const int off2 = coord_off[p * NB + b2];
        const int na   = n_acc[bt2];
        ok = (b2 != b1) && (min_sep[(p * NB + b1) * NB + b2] >= MIN_SEP);
        b2info[b2] = make_int2((bt2 & 0xffff) | (na << 16), off2);
    }
    const unsigned long long m = __ballot(ok);
    const int cnt = __popcll(m);
    if (ok) {
        const int pos = __popcll(m & ((1ull << ln) - 1ull));
        b2list[wv * BPW + pos] = wv * BPW + ln;
    }
    // same-wave LDS RAW: DS ops of a wave execute in order; compiler
    // inserts lgkmcnt waits. No __syncthreads needed.

    // ---- wave loop over its cnt*8 acceptor slots ----
    float energy = 0.0f;
    const int cnt8 = cnt * 8;
    for (int j = ln; j < cnt8; j += 64) {
        const int b2 = b2list[wv * BPW + (j >> 3)];
        const int a  = j & 7;
        const int2 info = b2info[b2];
        const int bt2 = info.x & 0xffff;
        const int na  = info.x >> 16;

        float hd0 = 0, hd1 = 0, hd2 = 0, hd3 = 0;
        int   hp0 = 0, hp1 = 0, hp2 = 0, hp3 = 0;
        int   nh = 0, hyb = 0;

        if (a < na) {
            const int ai    = acc_inds[bt2 * 8 + a];
            const int atype = acceptor_type[bt2 * 8 + a];
            hyb             = acceptor_hyb[bt2 * 8 + a];
            const float* Ac = coords + (size_t)(p * (NB * NA) + info.y + ai) * 3;
            const float ax = Ac[0], ay = Ac[1], az = Ac[2];

            #pragma unroll
            for (int dn = 0; dn < 4; ++dn) {
                const int dbits = __float_as_int(dv[dn].w);
                if (!(dbits & DVALID)) continue;   // wave-uniform
                const float dx = dv[dn].x - ax;
                const float dy = dv[dn].y - ay;
                const float dz = dv[dn].z - az;
                const float dd = sqrtf(dx * dx + dy * dy + dz * dz + 1e-12f);
                if (dd < cut) {
                    const int pp = (dbits & 0xff) + atype;
                    hd3 = (nh == 3) ? dd : hd3;  hp3 = (nh == 3) ? pp : hp3;
                    hd2 = (nh == 2) ? dd : hd2;  hp2 = (nh == 2) ? pp : hp2;
                    hd1 = (nh == 1) ? dd : hd1;  hp1 = (nh == 1) ? pp : hp1;
                    hd0 = (nh == 0) ? dd : hd0;  hp0 = (nh == 0) ? pp : hp0;
                    ++nh;
                }
            }
        }

        // rare Horner path (~1% of slots pass the distance filter)
        #pragma unroll
        for (int h = 0; h < 4; ++h) {
            if (!__any(h < nh)) break;
            if (h < nh) {
                const float dd = (h == 0) ? hd0 : (h == 1) ? hd1 : (h == 2) ? hd2 : hd3;
                const int   pp = (h == 0) ? hp0 : (h == 1) ? hp1 : (h == 2) ? hp2 : hp3;
                const float* c = pair_poly + pp * NPOLY;
                float ev = c[0];
                #pragma unroll
                for (int kk = 1; kk < NPOLY; ++kk) ev = ev * dd + c[kk];
                const float w = pair_params[pp * 3 + hyb];
                ev = fmaxf(fminf(ev, 0.0f), emin);
                energy += w * ev;
            }
        }
    }

    // ---- wave-local reduce, one pure write per wave ----
    #pragma unroll
    for (int off = 32; off >= 1; off >>= 1)
        energy += __shfl_down(energy, off, 64);
    if (ln == 0) partials[blockIdx.x * 4 + wv] = energy;
}

// 1 wg: wave wv sums poses 2wv, 2wv+1 (640 partials each, coalesced).
__global__ __launch_bounds__(256) void hbond_reduce(
    const float* __restrict__ partials, float* __restrict__ out)
{
    const int wv = threadIdx.x >> 6, ln = threadIdx.x & 63;
    #pragma unroll
    for (int q = 0; q < 2; ++q) {
        const int pose = wv * 2 + q;
        const float* base = partials + pose * NB * 4;   // 640 floats
        float v = 0.0f;
        #pragma unroll
        for (int r = 0; r < 10; ++r) v += base[r * 64 + ln];
        #pragma unroll
        for (int off = 32; off >= 1; off >>= 1)
            v += __shfl_down(v, off, 64);
        if (ln == 0) out[pose] = v;
    }
}

extern "C" void kernel_launch(void* const* d_in, const int* in_sizes, int n_in,
                              void* d_out, int out_size, void* d_ws, size_t ws_size,
                              hipStream_t stream) {
    const float* coords        = (const float*)d_in[0];
    // d_in[1] (dispatch) is the full (p, b1, b2) meshgrid — derived from blockIdx.
    const int*   coord_off     = (const int*)  d_in[2];
    const int*   block_type    = (const int*)  d_in[3];
    const int*   min_sep       = (const int*)  d_in[4];
    const int*   n_donH        = (const int*)  d_in[5];
    const int*   n_acc         = (const int*)  d_in[6];
    const int*   donH_inds     = (const int*)  d_in[7];
    const int*   acc_inds      = (const int*)  d_in[8];
    const int*   donor_type    = (const int*)  d_in[9];
    const int*   acceptor_type = (const int*)  d_in[10];
    const int*   acceptor_hyb  = (const int*)  d_in[11];
    const float* pair_params   = (const float*)d_in[12];
    const float* pair_poly     = (const float*)d_in[13];
    const float* gp            = (const float*)d_in[14];
    float*       partials      = (float*)d_ws;   // NWG*4 floats = 20480 B
    float*       out           = (float*)d_out;

    hbond_main<<<NWG, 256, 0, stream>>>(
        coords, coord_off, block_type, min_sep,
        n_donH, n_acc, donH_inds, acc_inds,
        donor_type, acceptor_type, acceptor_hyb,
        pair_params, pair_poly, gp, partials);

    hbond_reduce<<<1, 256, 0, stream>>>(partials, out);
}